// Round 12
// baseline (248.512 us; speedup 1.0000x reference)
//
#include <hip/hip_runtime.h>
#include <hip/hip_bf16.h>

#define BSZ  8
#define LSEQ 8192
#define DDIM 256
#define HDIM 1024
#define MFFT 4096   // half-size complex FFT length (N = 8192 real)

typedef __bf16 bf16;
typedef __bf16 bf16x8 __attribute__((ext_vector_type(8)));
typedef __bf16 bf16x4 __attribute__((ext_vector_type(4)));
typedef float  f32x4  __attribute__((ext_vector_type(4)));
typedef float  f32x16 __attribute__((ext_vector_type(16)));

__device__ __forceinline__ void wave_reduce2(float& a, float& b) {
    #pragma unroll
    for (int off = 1; off < 64; off <<= 1) {
        a += __shfl_xor(a, off);
        b += __shfl_xor(b, off);
    }
}

// async global->LDS 16B; LDS dest = wave-uniform base + lane*16 (linear).
__device__ __forceinline__ void gl_lds16(const void* g, void* l) {
    __builtin_amdgcn_global_load_lds(
        (const __attribute__((address_space(1))) unsigned int*)(unsigned long long)g,
        (__attribute__((address_space(3))) unsigned int*)(unsigned int)(unsigned long long)l,
        16, 0, 0);
}

// ---------------- K0: bf16 weights (k-group-major, 32-H chunks) + twiddles -
// W1K: [c 0..31][ks 0..7][grp 0..3][hh 0..31][j 0..7]   (chunk 16 KB)
//      element = w1[(ks*32+grp*8+j)][c*32+hh]           (16x16x32 B-frags)
// W2K: [c 0..31][ks4 0..1][g2 0..1][d 0..255][j 0..7]   (chunk 16 KB)
//      element = w2[(c*32 + ks4*16 + g2*8 + j)][d]      (32x32x16 B-frags)
// tbl layout (float2 units): [0..3583] stage0 planes (f-1)*512+j  (W_4096^{f j})
//   [3584..4031] stage1 planes (f-1)*64+j (W_512^{f j})
//   [4032..4087] stage2 planes (f-1)*8+j  (W_64^{f j})
//   [4088..8184] U[k] = (cos(pi k/4096), sin(pi k/4096)), k=0..4096
__global__ __launch_bounds__(256) void k0_prep(const float* __restrict__ w1,
                                               const float* __restrict__ w2,
                                               bf16* __restrict__ w1k,
                                               bf16* __restrict__ w2k,
                                               float2* __restrict__ tbl) {
    const int e = blockIdx.x * 256 + threadIdx.x;   // 0..262143
    {
        const int c = e >> 13, r = e & 8191;
        const int ks = r >> 10, grp = (r >> 8) & 3, hh = (r >> 3) & 31, j = r & 7;
        w1k[e] = (bf16)w1[(ks * 32 + grp * 8 + j) * HDIM + c * 32 + hh];
    }
    {
        const int c = e >> 13, r = e & 8191;
        const int ks4 = r >> 12, g2 = (r >> 11) & 1, d = (r >> 3) & 255, j = r & 7;
        w2k[e] = (bf16)w2[(c * 32 + ks4 * 16 + g2 * 8 + j) * DDIM + d];
    }
    if (e <= 8184) {
        float ang;
        if (e < 3584) {
            const int f = e / 512 + 1, jj = e & 511;
            ang = -6.283185307179586f * (float)(f * jj) * (1.0f / 4096.0f);
        } else if (e < 4032) {
            const int t = e - 3584, f = t / 64 + 1, jj = t & 63;
            ang = -6.283185307179586f * (float)(f * jj) * (1.0f / 512.0f);
        } else if (e < 4088) {
            const int t = e - 4032, f = t / 8 + 1, jj = t & 7;
            ang = -6.283185307179586f * (float)(f * jj) * (1.0f / 64.0f);
        } else {
            const int k = e - 4088;
            ang = 3.14159265358979323846f * (float)k * (1.0f / 4096.0f);
        }
        tbl[e] = make_float2(cosf(ang), sinf(ang));
    }
}

// ---------------- K1: LN1 + ReLU + eps, transposed write: ht(B,D,L) --------
__global__ __launch_bounds__(256) void k1_ln1_relu_T(const float* __restrict__ x,
                                                     const float* __restrict__ g1,
                                                     const float* __restrict__ b1,
                                                     float* __restrict__ ht) {
    __shared__ float tile[DDIM][33];   // [d][l] padded
    const int tid  = threadIdx.x;
    const int wave = tid >> 6, lane = tid & 63;
    const int b  = blockIdx.x >> 8;           // 256 l-tiles per batch
    const int l0 = (blockIdx.x & 255) << 5;
    const float4 g4 = *(const float4*)&g1[lane * 4];
    const float4 b4 = *(const float4*)&b1[lane * 4];
    for (int r8 = 0; r8 < 8; ++r8) {
        const int l = r8 * 4 + wave;
        const float4 v = *(const float4*)&x[(b * LSEQ + l0 + l) * DDIM + lane * 4];
        float s = v.x + v.y + v.z + v.w;
        float q = v.x * v.x + v.y * v.y + v.z * v.z + v.w * v.w;
        wave_reduce2(s, q);
        const float mean = s * (1.0f / 256.0f);
        const float var  = q * (1.0f / 256.0f) - mean * mean;
        const float rstd = rsqrtf(var + 1e-5f);
        const float vv[4] = {v.x, v.y, v.z, v.w};
        const float gg[4] = {g4.x, g4.y, g4.z, g4.w};
        const float bb[4] = {b4.x, b4.y, b4.z, b4.w};
        #pragma unroll
        for (int j = 0; j < 4; ++j) {
            float t = (vv[j] - mean) * rstd * gg[j] + bb[j];
            t = fmaxf(t, 0.0f) + 1e-6f;
            tile[lane * 4 + j][l] = t;
        }
    }
    __syncthreads();
    for (int i = tid; i < DDIM * 32; i += 256) {
        const int d = i >> 5, ll = i & 31;
        ht[(b * DDIM + d) * LSEQ + l0 + ll] = tile[d][ll];
    }
}

// ---------------- K2: per-channel SPSD1D, radix-8 + global twiddles --------
// Z physical layout XOR-swizzled (float2 units): zs(p)=p^((p>>4)&15)
__device__ __forceinline__ int zs(int p) { return p ^ ((p >> 4) & 15); }
__device__ __forceinline__ float2 cmulf(float2 a, float2 b) {
    return make_float2(fmaf(a.x, b.x, -a.y * b.y), fmaf(a.x, b.y, a.y * b.x));
}
__device__ __forceinline__ float2 f2add(float2 a, float2 b) { return make_float2(a.x + b.x, a.y + b.y); }
__device__ __forceinline__ float2 f2sub(float2 a, float2 b) { return make_float2(a.x - b.x, a.y - b.y); }
#define CSQ2 0.70710678118654752440f

// DFT8 (DIF network, natural-frequency outputs y0..y7)
__device__ __forceinline__ void dft8(float2 a0, float2 a1, float2 a2, float2 a3,
                                     float2 a4, float2 a5, float2 a6, float2 a7,
                                     float2& y0, float2& y1, float2& y2, float2& y3,
                                     float2& y4, float2& y5, float2& y6, float2& y7) {
    const float2 s0 = f2add(a0, a4), s1 = f2add(a1, a5), s2 = f2add(a2, a6), s3 = f2add(a3, a7);
    const float2 d0 = f2sub(a0, a4), d1 = f2sub(a1, a5), d2 = f2sub(a2, a6), d3 = f2sub(a3, a7);
    const float2 d1t = make_float2(CSQ2 * (d1.x + d1.y), CSQ2 * (d1.y - d1.x));   // * W8
    const float2 d2t = make_float2(d2.y, -d2.x);                                  // * -i
    const float2 d3t = make_float2(CSQ2 * (d3.y - d3.x), -CSQ2 * (d3.x + d3.y));  // * W8^3
    const float2 u0 = f2add(s0, s2), u1 = f2add(s1, s3);
    const float2 v0 = f2sub(s0, s2);
    const float2 sd = f2sub(s1, s3);
    const float2 v1 = make_float2(sd.y, -sd.x);                                   // * -i
    const float2 e0 = f2add(d0, d2t), e1 = f2add(d1t, d3t);
    const float2 f0 = f2sub(d0, d2t);
    const float2 dd = f2sub(d1t, d3t);
    const float2 f1 = make_float2(dd.y, -dd.x);                                   // * -i
    y0 = f2add(u0, u1); y4 = f2sub(u0, u1);
    y2 = f2add(v0, v1); y6 = f2sub(v0, v1);
    y1 = f2add(e0, e1); y5 = f2sub(e0, e1);
    y3 = f2add(f0, f1); y7 = f2sub(f0, f1);
}

// one radix-8 DIF stage; q = 1<<LQ, twiddle plane base TOFF (f-major, q-entry planes)
template<int LQ, int TOFF>
__device__ __forceinline__ void stage8(float2* Z, const float2* __restrict__ tw, int tid) {
    const int q = 1 << LQ;
    const int j = tid & (q - 1);
    const int base = ((tid >> LQ) << (LQ + 3)) + j;
    const float2 a0 = Z[zs(base)],         a1 = Z[zs(base + q)];
    const float2 a2 = Z[zs(base + 2 * q)], a3 = Z[zs(base + 3 * q)];
    const float2 a4 = Z[zs(base + 4 * q)], a5 = Z[zs(base + 5 * q)];
    const float2 a6 = Z[zs(base + 6 * q)], a7 = Z[zs(base + 7 * q)];
    float2 y0, y1, y2, y3, y4, y5, y6, y7;
    dft8(a0, a1, a2, a3, a4, a5, a6, a7, y0, y1, y2, y3, y4, y5, y6, y7);
    y1 = cmulf(y1, tw[TOFF + j]);
    y2 = cmulf(y2, tw[TOFF + q + j]);
    y3 = cmulf(y3, tw[TOFF + 2 * q + j]);
    y4 = cmulf(y4, tw[TOFF + 3 * q + j]);
    y5 = cmulf(y5, tw[TOFF + 4 * q + j]);
    y6 = cmulf(y6, tw[TOFF + 5 * q + j]);
    y7 = cmulf(y7, tw[TOFF + 6 * q + j]);
    Z[zs(base)]         = y0;   // slot rev3(0)=0
    Z[zs(base + 4 * q)] = y1;   // rev3(1)=4
    Z[zs(base + 2 * q)] = y2;   // rev3(2)=2
    Z[zs(base + 6 * q)] = y3;   // rev3(3)=6
    Z[zs(base + q)]     = y4;   // rev3(4)=1
    Z[zs(base + 5 * q)] = y5;   // rev3(5)=5
    Z[zs(base + 3 * q)] = y6;   // rev3(6)=3
    Z[zs(base + 7 * q)] = y7;   // rev3(7)=7
    __syncthreads();
}

// last stage (m=8, q=1, j=0: no twiddles) with folded rev12 scatter-write
__device__ __forceinline__ void stage8_last(float2* Z, int tid) {
    const int base = tid << 3;
    const float2 a0 = Z[zs(base)],     a1 = Z[zs(base + 1)];
    const float2 a2 = Z[zs(base + 2)], a3 = Z[zs(base + 3)];
    const float2 a4 = Z[zs(base + 4)], a5 = Z[zs(base + 5)];
    const float2 a6 = Z[zs(base + 6)], a7 = Z[zs(base + 7)];
    __syncthreads();
    float2 y0, y1, y2, y3, y4, y5, y6, y7;
    dft8(a0, a1, a2, a3, a4, a5, a6, a7, y0, y1, y2, y3, y4, y5, y6, y7);
    const int r9 = (int)(__brev((unsigned)tid) >> 23);
    Z[zs(r9)]        = y0;
    Z[zs(512 + r9)]  = y1;
    Z[zs(1024 + r9)] = y2;
    Z[zs(1536 + r9)] = y3;
    Z[zs(2048 + r9)] = y4;
    Z[zs(2560 + r9)] = y5;
    Z[zs(3072 + r9)] = y6;
    Z[zs(3584 + r9)] = y7;
    __syncthreads();
}

// full forward 4096-pt FFT: natural in -> natural out (bins)
__device__ __forceinline__ void fft4096(float2* Z, const float2* __restrict__ tw, int tid) {
    stage8<9, 0>(Z, tw, tid);
    stage8<6, 3584>(Z, tw, tid);
    stage8<3, 4032>(Z, tw, tid);
    stage8_last(Z, tid);
}

__global__ __launch_bounds__(512, 4) void k2_spsd(float* __restrict__ ht,
                                                  const float2* __restrict__ tw) {
    __shared__ float2 Z[MFFT];        // 32 KB, swizzled, natural bin order between FFTs
    __shared__ float  mg[MFFT + 1];   // 16.4 KB
    const int tid = threadIdx.x;
    float* row = ht + (size_t)blockIdx.x * LSEQ;
    const float2* U = tw + 4088;

    for (int m = tid; m < MFFT; m += 512)
        Z[zs(m)] = *(const float2*)&row[2 * m];
    __syncthreads();

    fft4096(Z, tw, tid);              // forward FFT of packed even+i*odd

    // Pass A: magnitudes of rfft bins 0..4096
    for (int k = tid; k <= MFFT; k += 512) {
        const int ka = k & (MFFT - 1);
        const int kb = (MFFT - k) & (MFFT - 1);
        const float2 A = Z[zs(ka)], Bc = Z[zs(kb)];
        const float zex = 0.5f * (A.x + Bc.x), zey = 0.5f * (A.y - Bc.y);
        const float zox = 0.5f * (A.y + Bc.y), zoy = -0.5f * (A.x - Bc.x);
        const float2 u = U[k];
        const float cs = u.x, sn = -u.y;       // e^{-i pi k/4096}
        const float xr = zex + zox * cs - zoy * sn;
        const float xi = zey + zox * sn + zoy * cs;
        mg[k] = sqrtf(xr * xr + xi * xi);
    }
    __syncthreads();

    // Pass B: mask + rebuild filtered half-spectrum in place; write CONJ
    for (int k = tid; k <= 2048; k += 512) {
        const int km = (MFFT - k) & (MFFT - 1);
        const float2 Pk = Z[zs(k)];
        const float2 Pm = Z[zs(km)];
        const float2 u = U[k];
        const float cs = u.x, sn = u.y;        // theta = +pi k/4096
        const float zex = 0.5f * (Pk.x + Pm.x), zey = 0.5f * (Pk.y - Pm.y);
        const float zox = 0.5f * (Pk.y + Pm.y), zoy = -0.5f * (Pk.x - Pm.x);
        float xkr = zex + zox * cs + zoy * sn;
        float xki = zey - zox * sn + zoy * cs;
        const float zex2 = 0.5f * (Pm.x + Pk.x), zey2 = 0.5f * (Pm.y - Pk.y);
        const float zox2 = 0.5f * (Pm.y + Pk.y), zoy2 = -0.5f * (Pm.x - Pk.x);
        float xmr = zex2 - zox2 * cs + zoy2 * sn;
        float xmi = zey2 - zox2 * sn - zoy2 * cs;
        const int jm = MFFT - k;
        bool keepk, keepm;
        {
            const int lo = (k - 3 < 0) ? 0 : k - 3;
            const int hi = (k + 4 > 4096) ? 4096 : k + 4;
            float mx = mg[k];
            for (int t2 = lo; t2 <= hi; ++t2) mx = fmaxf(mx, mg[t2]);
            keepk = (k < 3) || (mg[k] >= mx);
        }
        {
            const int hi = (jm + 4 > 4096) ? 4096 : jm + 4;
            float mx = mg[jm];
            for (int t2 = jm - 3; t2 <= hi; ++t2) mx = fmaxf(mx, mg[t2]);
            keepm = (mg[jm] >= mx);
        }
        if (!keepk) { xkr = 0.0f; xki = 0.0f; }
        if (!keepm) { xmr = 0.0f; xmi = 0.0f; }
        const float zpex = 0.5f * (xkr + xmr), zpey = 0.5f * (xki - xmi);
        const float dfx  = 0.5f * (xkr - xmr), dfy  = 0.5f * (xki + xmi);
        const float zpox = dfx * cs - dfy * sn, zpoy = dfx * sn + dfy * cs;
        const float2 zk = make_float2(zpex - zpoy, zpey + zpox);
        const float zex3 = 0.5f * (xmr + xkr), zey3 = 0.5f * (xmi - xki);
        const float df2x = 0.5f * (xmr - xkr), df2y = 0.5f * (xmi + xki);
        const float zo3x = -df2x * cs - df2y * sn, zo3y = df2x * sn - df2y * cs;
        const float2 zm = make_float2(zex3 - zo3y, zey3 + zo3x);
        Z[zs(k)] = make_float2(zk.x, -zk.y);
        if (k != 0 && k != 2048) Z[zs(MFFT - k)] = make_float2(zm.x, -zm.y);
    }
    __syncthreads();

    fft4096(Z, tw, tid);              // FFT(conj(Z')) -> conj + scale at store

    const float invM = 1.0f / (float)MFFT;
    for (int m = tid; m < MFFT; m += 512) {
        const float2 z = Z[zs(m)];
        *(float2*)&row[2 * m] = make_float2(z.x * invM, -z.y * invM);
    }
}

// ---------------- K3: transpose back * filt_w, LN2, cast bf16 --------------
__global__ __launch_bounds__(256) void k3_filt_ln2(const float* __restrict__ ht,
                                                   const float* __restrict__ fw,
                                                   const float* __restrict__ g2,
                                                   const float* __restrict__ b2,
                                                   bf16* __restrict__ aln) {
    __shared__ float tile[DDIM][33];
    const int tid  = threadIdx.x;
    const int wave = tid >> 6, lane = tid & 63;
    const int b  = blockIdx.x >> 8;
    const int l0 = (blockIdx.x & 255) << 5;
    for (int i = tid; i < DDIM * 32; i += 256) {
        const int d = i >> 5, ll = i & 31;
        tile[d][ll] = ht[(b * DDIM + d) * LSEQ + l0 + ll];
    }
    __syncthreads();
    const float4 g4 = *(const float4*)&g2[lane * 4];
    const float4 bb4 = *(const float4*)&b2[lane * 4];
    for (int r8 = 0; r8 < 8; ++r8) {
        const int l = r8 * 4 + wave;
        const int gl = l0 + l;
        const float4 f4 = *(const float4*)&fw[gl * DDIM + lane * 4];
        float v[4];
        v[0] = tile[lane * 4 + 0][l] * f4.x;
        v[1] = tile[lane * 4 + 1][l] * f4.y;
        v[2] = tile[lane * 4 + 2][l] * f4.z;
        v[3] = tile[lane * 4 + 3][l] * f4.w;
        float s = v[0] + v[1] + v[2] + v[3];
        float q = v[0] * v[0] + v[1] * v[1] + v[2] * v[2] + v[3] * v[3];
        wave_reduce2(s, q);
        const float mean = s * (1.0f / 256.0f);
        const float var  = q * (1.0f / 256.0f) - mean * mean;
        const float rstd = rsqrtf(var + 1e-5f);
        const float gg[4] = {g4.x, g4.y, g4.z, g4.w};
        const float bb[4] = {bb4.x, bb4.y, bb4.z, bb4.w};
        bf16x4 o;
        #pragma unroll
        for (int j = 0; j < 4; ++j)
            o[j] = (bf16)((v[j] - mean) * rstd * gg[j] + bb[j]);
        *(bf16x4*)&aln[(b * LSEQ + gl) * DDIM + lane * 4] = o;
    }
}

// ---------------- K4: fused MLP, 32-H chunks, DOUBLE-BUFFERED W1/W2 --------
// Block 64 rows, 8 waves. G1: 4M x 2N 16x16x32 (A-resident, 8 reads/chunk).
// G2: 2M x 4N 32x32x16 (2 ks4 x 3 reads). Staging of chunk c+1 issued BEFORE
// G1(c); barrier A's vmcnt drain is covered by G1+gelu (~1000+ cyc) instead
// of exposed (the r7-r11 invariant ~113 us was this drain).
// LDS: W1 2 x 16 KB @0; W2 2 x 16 KB @32768; lM 4 KB @65536 => 68 KB.
#define LDS_W1 0
#define LDS_W2 32768
#define LDS_LM 65536
#define LDS_TOT 69632

#define MFMA16 __builtin_amdgcn_mfma_f32_16x16x32_bf16
#define MFMA32 __builtin_amdgcn_mfma_f32_32x32x16_bf16

__global__ __launch_bounds__(512, 4) void k4_mlp(const bf16* __restrict__ aln,
                                                 const bf16* __restrict__ w1k,
                                                 const bf16* __restrict__ w2k,
                                                 const float* __restrict__ bb1,
                                                 const float* __restrict__ bb2,
                                                 const float* __restrict__ x,
                                                 float* __restrict__ out) {
    extern __shared__ char sm[];
    const int tid = threadIdx.x;
    const int lane = tid & 63, w = tid >> 6;
    const int rowLane = lane & 15, grp = lane >> 4;
    const int wm1 = w >> 1, wn1 = w & 1;      // G1 role: 4M x 2N, 16-row waves
    const int wm2 = w >> 2, wn2 = w & 3;      // G2 role: 2M x 4N, 32-row waves
    const int lane32 = lane & 31, g2l = lane >> 5;
    const int row0 = blockIdx.x << 6;         // 64 rows per block

    // A fragments: wave's 16 rows x 256 K slice, 32 VGPRs (r7/r10-proven)
    bf16x8 aF[8];
    {
        const size_t rb = (size_t)(row0 + wm1 * 16 + rowLane) * DDIM;
        #pragma unroll
        for (int ks = 0; ks < 8; ++ks)
            aF[ks] = *(const bf16x8*)(aln + rb + ks * 32 + grp * 8);
    }
    // prologue: stage chunk 0 (W1 16 KB + W2 16 KB) into buffer 0
    {
        const char* g1 = (const char*)w1k;
        gl_lds16(g1 + tid * 16, sm + LDS_W1 + tid * 16);
        gl_lds16(g1 + 8192 + tid * 16, sm + LDS_W1 + 8192 + tid * 16);
        const char* g2p = (const char*)w2k;
        gl_lds16(g2p + tid * 16, sm + LDS_W2 + tid * 16);
        gl_lds16(g2p + 8192 + tid * 16, sm + LDS_W2 + 8192 + tid * 16);
    }
    __syncthreads();

    f32x16 acc0, acc1;
    #pragma unroll
    for (int i = 0; i < 16; ++i) { acc0[i] = 0.f; acc1[i] = 0.f; }

    for (int c = 0; c < 32; ++c) {
        const int pb = (c & 1) << 14;          // current buffer byte offset
        // issue stage of chunk c+1 into the OTHER buffer (its last readers
        // finished before the previous barrier B -> safe)
        if (c < 31) {
            const int nb = ((c + 1) & 1) << 14;
            const char* g1 = (const char*)w1k + (size_t)(c + 1) * 16384;
            gl_lds16(g1 + tid * 16, sm + LDS_W1 + nb + tid * 16);
            gl_lds16(g1 + 8192 + tid * 16, sm + LDS_W1 + nb + 8192 + tid * 16);
            const char* g2p = (const char*)w2k + (size_t)(c + 1) * 16384;
            gl_lds16(g2p + tid * 16, sm + LDS_W2 + nb + tid * 16);
            gl_lds16(g2p + 8192 + tid * 16, sm + LDS_W2 + nb + 8192 + tid * 16);
        }
        const int hc = wn1 * 16 + rowLane;     // 0..31 within chunk

        // ---- GEMM1: P(16x16/wave) = Areg(16x256) x W1c from buf[c&1]
        f32x4 p0 = {0.f, 0.f, 0.f, 0.f};
        #pragma unroll
        for (int ks = 0; ks < 8; ++ks) {
            const bf16x8 bF = *(const bf16x8*)(sm + LDS_W1 + pb + ks * 2048 + grp * 512 + hc * 16);
            p0 = MFMA16(aF[ks], bF, p0, 0, 0, 0);
        }
        // ---- bias + exact gelu -> lM [plane = hc>>3][row][8]
        {
            const float bias = bb1[c * 32 + hc];
            const int base = (hc >> 3) * 1024 + (hc & 7) * 2;
            #pragma unroll
            for (int j = 0; j < 4; ++j) {
                const int prow = wm1 * 16 + grp * 4 + j;
                const float v = p0[j] + bias;
                const float ge = 0.5f * v * (1.0f + erff(v * 0.70710678118654752f));
                *(bf16*)(sm + LDS_LM + base + prow * 16) = (bf16)ge;
            }
        }
        __syncthreads();   // barrier A: lM visible; staging(c+1) drain covered by G1+gelu
        // ---- GEMM2 (32x32x16): acc(32x64/wave) += lM(32 rows k) x W2c buf[c&1]
        #pragma unroll
        for (int ks4 = 0; ks4 < 2; ++ks4) {
            const int plane = ks4 * 2 + g2l;
            const bf16x8 aM = *(const bf16x8*)(sm + LDS_LM + plane * 1024 + (wm2 * 32 + lane32) * 16);
            const bf16x8 bw0 = *(const bf16x8*)(sm + LDS_W2 + pb + (plane * 256 + wn2 * 64 + lane32) * 16);
            const bf16x8 bw1 = *(const bf16x8*)(sm + LDS_W2 + pb + (plane * 256 + wn2 * 64 + 32 + lane32) * 16);
            acc0 = MFMA32(aM, bw0, acc0, 0, 0, 0);
            acc1 = MFMA32(aM, bw1, acc1, 0, 0, 0);
        }
        __syncthreads();   // barrier B: lM + buf[(c+1)&1] parity free for next chunk
    }
    // ---- epilogue: +bb2 + residual.  32x32 C/D: col=lane&31,
    // row = (reg&3) + 8*(reg>>2) + 4*(lane>>5)   [m74/m101 verified]
    #pragma unroll
    for (int fn = 0; fn < 2; ++fn) {
        const int dcol = wn2 * 64 + fn * 32 + lane32;
        const float b2v = bb2[dcol];
        #pragma unroll
        for (int reg = 0; reg < 16; ++reg) {
            const int orow = row0 + wm2 * 32 + (reg & 3) + 8 * (reg >> 2) + 4 * g2l;
            const int gi = orow * DDIM + dcol;
            const float a = fn ? acc1[reg] : acc0[reg];
            out[gi] = a + b2v + x[gi];
        }
    }
}

extern "C" void kernel_launch(void* const* d_in, const int* in_sizes, int n_in,
                              void* d_out, int out_size, void* d_ws, size_t ws_size,
                              hipStream_t stream) {
    (void)in_sizes; (void)n_in; (void)out_size; (void)ws_size;
    const float* x   = (const float*)d_in[0];
    const float* g1  = (const float*)d_in[1];
    const float* b1  = (const float*)d_in[2];
    const float* g2  = (const float*)d_in[3];
    const float* b2  = (const float*)d_in[4];
    const float* fw  = (const float*)d_in[5];
    const float* w1  = (const float*)d_in[6];
    const float* bb1 = (const float*)d_in[7];
    const float* w2  = (const float*)d_in[8];
    const float* bb2 = (const float*)d_in[9];
    float* out = (float*)d_out;
    char*  ws  = (char*)d_ws;

    bf16*   aln = (bf16*)ws;                             // 33554432 B
    bf16*   w1k = (bf16*)(ws + (size_t)33554432);        //   524288 B
    bf16*   w2k = (bf16*)(ws + (size_t)34078720);        //   524288 B
    float2* tbl = (float2*)(ws + (size_t)34603008);      //    65480 B
    float* ht = out;                                     // reuse d_out as (B,D,L) scratch

    k0_prep<<<dim3(1024), dim3(256), 0, stream>>>(w1, w2, w1k, w2k, tbl);
    k1_ln1_relu_T<<<dim3(2048), dim3(256), 0, stream>>>(x, g1, b1, ht);
    k2_spsd<<<dim3(2048), dim3(512), 0, stream>>>(ht, tbl);
    k3_filt_ln2<<<dim3(2048), dim3(256), 0, stream>>>(ht, fw, g2, b2, aln);
    k4_mlp<<<dim3(1024), dim3(512), LDS_TOT, stream>>>(aln, w1k, w2k, bb1, bb2, x, out);
}

// Round 13
// 234.432 us; speedup vs baseline: 1.0601x; 1.0601x over previous
//
#include <hip/hip_runtime.h>
#include <hip/hip_bf16.h>

#define BSZ  8
#define LSEQ 8192
#define DDIM 256
#define HDIM 1024
#define MFFT 4096   // half-size complex FFT length (N = 8192 real)

typedef __bf16 bf16;
typedef __bf16 bf16x8 __attribute__((ext_vector_type(8)));
typedef __bf16 bf16x4 __attribute__((ext_vector_type(4)));
typedef float  f32x4  __attribute__((ext_vector_type(4)));
typedef float  f32x16 __attribute__((ext_vector_type(16)));

__device__ __forceinline__ void wave_reduce2(float& a, float& b) {
    #pragma unroll
    for (int off = 1; off < 64; off <<= 1) {
        a += __shfl_xor(a, off);
        b += __shfl_xor(b, off);
    }
}

// async global->LDS 16B; LDS dest = wave-uniform base + lane*16 (linear).
__device__ __forceinline__ void gl_lds16(const void* g, void* l) {
    __builtin_amdgcn_global_load_lds(
        (const __attribute__((address_space(1))) unsigned int*)(unsigned long long)g,
        (__attribute__((address_space(3))) unsigned int*)(unsigned int)(unsigned long long)l,
        16, 0, 0);
}

// ---------------- K0: bf16 weights (k-group-major, 64-H chunks) + twiddles -
// W1K: [c 0..15][ks 0..7][grp 0..3][hh 0..63][j 0..7]   (chunk 32 KB)
//      element = w1[(ks*32+grp*8+j)][c*64+hh]           (16x16x32 B-frags)
// W2K: [c 0..15][ks4 0..3][g2 0..1][d 0..255][j 0..7]   (chunk 32 KB)
//      element = w2[(c*64 + ks4*16 + g2*8 + j)][d]      (32x32x16 B-frags)
// tbl layout (float2 units): [0..3583] stage0 planes (f-1)*512+j  (W_4096^{f j})
//   [3584..4031] stage1 planes (f-1)*64+j (W_512^{f j})
//   [4032..4087] stage2 planes (f-1)*8+j  (W_64^{f j})
//   [4088..8184] U[k] = (cos(pi k/4096), sin(pi k/4096)), k=0..4096
__global__ __launch_bounds__(256) void k0_prep(const float* __restrict__ w1,
                                               const float* __restrict__ w2,
                                               bf16* __restrict__ w1k,
                                               bf16* __restrict__ w2k,
                                               float2* __restrict__ tbl) {
    const int e = blockIdx.x * 256 + threadIdx.x;   // 0..262143
    {
        const int c = e >> 14, r = e & 16383;
        const int ks = r >> 11, grp = (r >> 9) & 3, hh = (r >> 3) & 63, j = r & 7;
        w1k[e] = (bf16)w1[(ks * 32 + grp * 8 + j) * HDIM + c * 64 + hh];
    }
    {
        const int c = e >> 14, r = e & 16383;
        const int ks4 = r >> 12, g2 = (r >> 11) & 1, d = (r >> 3) & 255, j = r & 7;
        w2k[e] = (bf16)w2[(c * 64 + ks4 * 16 + g2 * 8 + j) * DDIM + d];
    }
    if (e <= 8184) {
        float ang;
        if (e < 3584) {
            const int f = e / 512 + 1, jj = e & 511;
            ang = -6.283185307179586f * (float)(f * jj) * (1.0f / 4096.0f);
        } else if (e < 4032) {
            const int t = e - 3584, f = t / 64 + 1, jj = t & 63;
            ang = -6.283185307179586f * (float)(f * jj) * (1.0f / 512.0f);
        } else if (e < 4088) {
            const int t = e - 4032, f = t / 8 + 1, jj = t & 7;
            ang = -6.283185307179586f * (float)(f * jj) * (1.0f / 64.0f);
        } else {
            const int k = e - 4088;
            ang = 3.14159265358979323846f * (float)k * (1.0f / 4096.0f);
        }
        tbl[e] = make_float2(cosf(ang), sinf(ang));
    }
}

// ---------------- K1: LN1 + ReLU + eps, transposed write: ht(B,D,L) --------
__global__ __launch_bounds__(256) void k1_ln1_relu_T(const float* __restrict__ x,
                                                     const float* __restrict__ g1,
                                                     const float* __restrict__ b1,
                                                     float* __restrict__ ht) {
    __shared__ float tile[DDIM][33];   // [d][l] padded
    const int tid  = threadIdx.x;
    const int wave = tid >> 6, lane = tid & 63;
    const int b  = blockIdx.x >> 8;           // 256 l-tiles per batch
    const int l0 = (blockIdx.x & 255) << 5;
    const float4 g4 = *(const float4*)&g1[lane * 4];
    const float4 b4 = *(const float4*)&b1[lane * 4];
    for (int r8 = 0; r8 < 8; ++r8) {
        const int l = r8 * 4 + wave;
        const float4 v = *(const float4*)&x[(b * LSEQ + l0 + l) * DDIM + lane * 4];
        float s = v.x + v.y + v.z + v.w;
        float q = v.x * v.x + v.y * v.y + v.z * v.z + v.w * v.w;
        wave_reduce2(s, q);
        const float mean = s * (1.0f / 256.0f);
        const float var  = q * (1.0f / 256.0f) - mean * mean;
        const float rstd = rsqrtf(var + 1e-5f);
        const float vv[4] = {v.x, v.y, v.z, v.w};
        const float gg[4] = {g4.x, g4.y, g4.z, g4.w};
        const float bb[4] = {b4.x, b4.y, b4.z, b4.w};
        #pragma unroll
        for (int j = 0; j < 4; ++j) {
            float t = (vv[j] - mean) * rstd * gg[j] + bb[j];
            t = fmaxf(t, 0.0f) + 1e-6f;
            tile[lane * 4 + j][l] = t;
        }
    }
    __syncthreads();
    for (int i = tid; i < DDIM * 32; i += 256) {
        const int d = i >> 5, ll = i & 31;
        ht[(b * DDIM + d) * LSEQ + l0 + ll] = tile[d][ll];
    }
}

// ---------------- K2: per-channel SPSD1D, radix-8 + global twiddles --------
// Z physical layout XOR-swizzled (float2 units): zs(p)=p^((p>>4)&15)
__device__ __forceinline__ int zs(int p) { return p ^ ((p >> 4) & 15); }
__device__ __forceinline__ float2 cmulf(float2 a, float2 b) {
    return make_float2(fmaf(a.x, b.x, -a.y * b.y), fmaf(a.x, b.y, a.y * b.x));
}
__device__ __forceinline__ float2 f2add(float2 a, float2 b) { return make_float2(a.x + b.x, a.y + b.y); }
__device__ __forceinline__ float2 f2sub(float2 a, float2 b) { return make_float2(a.x - b.x, a.y - b.y); }
#define CSQ2 0.70710678118654752440f

// DFT8 (DIF network, natural-frequency outputs y0..y7)
__device__ __forceinline__ void dft8(float2 a0, float2 a1, float2 a2, float2 a3,
                                     float2 a4, float2 a5, float2 a6, float2 a7,
                                     float2& y0, float2& y1, float2& y2, float2& y3,
                                     float2& y4, float2& y5, float2& y6, float2& y7) {
    const float2 s0 = f2add(a0, a4), s1 = f2add(a1, a5), s2 = f2add(a2, a6), s3 = f2add(a3, a7);
    const float2 d0 = f2sub(a0, a4), d1 = f2sub(a1, a5), d2 = f2sub(a2, a6), d3 = f2sub(a3, a7);
    const float2 d1t = make_float2(CSQ2 * (d1.x + d1.y), CSQ2 * (d1.y - d1.x));   // * W8
    const float2 d2t = make_float2(d2.y, -d2.x);                                  // * -i
    const float2 d3t = make_float2(CSQ2 * (d3.y - d3.x), -CSQ2 * (d3.x + d3.y));  // * W8^3
    const float2 u0 = f2add(s0, s2), u1 = f2add(s1, s3);
    const float2 v0 = f2sub(s0, s2);
    const float2 sd = f2sub(s1, s3);
    const float2 v1 = make_float2(sd.y, -sd.x);                                   // * -i
    const float2 e0 = f2add(d0, d2t), e1 = f2add(d1t, d3t);
    const float2 f0 = f2sub(d0, d2t);
    const float2 dd = f2sub(d1t, d3t);
    const float2 f1 = make_float2(dd.y, -dd.x);                                   // * -i
    y0 = f2add(u0, u1); y4 = f2sub(u0, u1);
    y2 = f2add(v0, v1); y6 = f2sub(v0, v1);
    y1 = f2add(e0, e1); y5 = f2sub(e0, e1);
    y3 = f2add(f0, f1); y7 = f2sub(f0, f1);
}

// one radix-8 DIF stage; q = 1<<LQ, twiddle plane base TOFF (f-major, q-entry planes)
template<int LQ, int TOFF>
__device__ __forceinline__ void stage8(float2* Z, const float2* __restrict__ tw, int tid) {
    const int q = 1 << LQ;
    const int j = tid & (q - 1);
    const int base = ((tid >> LQ) << (LQ + 3)) + j;
    const float2 a0 = Z[zs(base)],         a1 = Z[zs(base + q)];
    const float2 a2 = Z[zs(base + 2 * q)], a3 = Z[zs(base + 3 * q)];
    const float2 a4 = Z[zs(base + 4 * q)], a5 = Z[zs(base + 5 * q)];
    const float2 a6 = Z[zs(base + 6 * q)], a7 = Z[zs(base + 7 * q)];
    float2 y0, y1, y2, y3, y4, y5, y6, y7;
    dft8(a0, a1, a2, a3, a4, a5, a6, a7, y0, y1, y2, y3, y4, y5, y6, y7);
    y1 = cmulf(y1, tw[TOFF + j]);
    y2 = cmulf(y2, tw[TOFF + q + j]);
    y3 = cmulf(y3, tw[TOFF + 2 * q + j]);
    y4 = cmulf(y4, tw[TOFF + 3 * q + j]);
    y5 = cmulf(y5, tw[TOFF + 4 * q + j]);
    y6 = cmulf(y6, tw[TOFF + 5 * q + j]);
    y7 = cmulf(y7, tw[TOFF + 6 * q + j]);
    Z[zs(base)]         = y0;   // slot rev3(0)=0
    Z[zs(base + 4 * q)] = y1;   // rev3(1)=4
    Z[zs(base + 2 * q)] = y2;   // rev3(2)=2
    Z[zs(base + 6 * q)] = y3;   // rev3(3)=6
    Z[zs(base + q)]     = y4;   // rev3(4)=1
    Z[zs(base + 5 * q)] = y5;   // rev3(5)=5
    Z[zs(base + 3 * q)] = y6;   // rev3(6)=3
    Z[zs(base + 7 * q)] = y7;   // rev3(7)=7
    __syncthreads();
}

// FUSED first forward stage (q=512): reads its 8 inputs DIRECTLY from global
// (row[2*(tid + f*512)], perfectly coalesced) -- removes the separate load
// loop, one LDS round trip and one barrier.
__device__ __forceinline__ void stage8_first_global(float2* Z, const float2* __restrict__ tw,
                                                    int tid, const float* __restrict__ row) {
    const int j = tid;                 // 512 threads, one butterfly each
    const float2 a0 = *(const float2*)&row[2 * j];
    const float2 a1 = *(const float2*)&row[2 * (j + 512)];
    const float2 a2 = *(const float2*)&row[2 * (j + 1024)];
    const float2 a3 = *(const float2*)&row[2 * (j + 1536)];
    const float2 a4 = *(const float2*)&row[2 * (j + 2048)];
    const float2 a5 = *(const float2*)&row[2 * (j + 2560)];
    const float2 a6 = *(const float2*)&row[2 * (j + 3072)];
    const float2 a7 = *(const float2*)&row[2 * (j + 3584)];
    float2 y0, y1, y2, y3, y4, y5, y6, y7;
    dft8(a0, a1, a2, a3, a4, a5, a6, a7, y0, y1, y2, y3, y4, y5, y6, y7);
    y1 = cmulf(y1, tw[j]);
    y2 = cmulf(y2, tw[512 + j]);
    y3 = cmulf(y3, tw[1024 + j]);
    y4 = cmulf(y4, tw[1536 + j]);
    y5 = cmulf(y5, tw[2048 + j]);
    y6 = cmulf(y6, tw[2560 + j]);
    y7 = cmulf(y7, tw[3072 + j]);
    Z[zs(j)]        = y0;
    Z[zs(j + 2048)] = y1;   // rev3 slots, q=512
    Z[zs(j + 1024)] = y2;
    Z[zs(j + 3072)] = y3;
    Z[zs(j + 512)]  = y4;
    Z[zs(j + 2560)] = y5;
    Z[zs(j + 1536)] = y6;
    Z[zs(j + 3584)] = y7;
    __syncthreads();
}

// last stage (m=8, q=1, j=0: no twiddles) with folded rev12 scatter-write
__device__ __forceinline__ void stage8_last(float2* Z, int tid) {
    const int base = tid << 3;
    const float2 a0 = Z[zs(base)],     a1 = Z[zs(base + 1)];
    const float2 a2 = Z[zs(base + 2)], a3 = Z[zs(base + 3)];
    const float2 a4 = Z[zs(base + 4)], a5 = Z[zs(base + 5)];
    const float2 a6 = Z[zs(base + 6)], a7 = Z[zs(base + 7)];
    __syncthreads();
    float2 y0, y1, y2, y3, y4, y5, y6, y7;
    dft8(a0, a1, a2, a3, a4, a5, a6, a7, y0, y1, y2, y3, y4, y5, y6, y7);
    const int r9 = (int)(__brev((unsigned)tid) >> 23);
    Z[zs(r9)]        = y0;
    Z[zs(512 + r9)]  = y1;
    Z[zs(1024 + r9)] = y2;
    Z[zs(1536 + r9)] = y3;
    Z[zs(2048 + r9)] = y4;
    Z[zs(2560 + r9)] = y5;
    Z[zs(3072 + r9)] = y6;
    Z[zs(3584 + r9)] = y7;
    __syncthreads();
}

// forward 4096-pt FFT with fused global first stage
__device__ __forceinline__ void fft4096_fwd(float2* Z, const float2* __restrict__ tw,
                                            int tid, const float* __restrict__ row) {
    stage8_first_global(Z, tw, tid, row);
    stage8<6, 3584>(Z, tw, tid);
    stage8<3, 4032>(Z, tw, tid);
    stage8_last(Z, tid);
}

// full in-LDS 4096-pt FFT (used for the inverse): natural in -> natural out
__device__ __forceinline__ void fft4096(float2* Z, const float2* __restrict__ tw, int tid) {
    stage8<9, 0>(Z, tw, tid);
    stage8<6, 3584>(Z, tw, tid);
    stage8<3, 4032>(Z, tw, tid);
    stage8_last(Z, tid);
}

__global__ __launch_bounds__(512, 4) void k2_spsd(float* __restrict__ ht,
                                                  const float2* __restrict__ tw) {
    __shared__ float2 Z[MFFT];        // 32 KB, swizzled, natural bin order between FFTs
    __shared__ float  mg[MFFT + 1];   // 16.4 KB, SQUARED magnitudes
    const int tid = threadIdx.x;
    float* row = ht + (size_t)blockIdx.x * LSEQ;
    const float2* U = tw + 4088;

    fft4096_fwd(Z, tw, tid, row);     // forward FFT of packed even+i*odd (global-fused)

    // Pass A (paired): for each k in [0,2048], unpack BOTH rfft bins (k, 4096-k)
    // from the shared intermediates, store squared mags, and overwrite Z with
    // the UNPACKED spectrum (pairs are thread-private -> race-free).
    // k==0 packs the two real values (X0.re, X4096.re) into slot 0.
    for (int k = tid; k <= 2048; k += 512) {
        const int km = (MFFT - k) & (MFFT - 1);
        const float2 Pk = Z[zs(k)];
        const float2 Pm = Z[zs(km)];
        const float2 u = U[k];
        const float cs = u.x, sn = u.y;        // theta = +pi k/4096
        const float zex = 0.5f * (Pk.x + Pm.x), zey = 0.5f * (Pk.y - Pm.y);
        const float zox = 0.5f * (Pk.y + Pm.y), zoy = -0.5f * (Pk.x - Pm.x);
        const float xkr = zex + zox * cs + zoy * sn;
        const float xki = zey - zox * sn + zoy * cs;
        const float xmr = zex - zox * cs - zoy * sn;
        const float xmi = -zey - zox * sn + zoy * cs;
        mg[k]        = xkr * xkr + xki * xki;
        mg[MFFT - k] = xmr * xmr + xmi * xmi;
        if (k == 0) {
            Z[zs(0)] = make_float2(xkr, xmr);  // (X0.re, X4096.re); imags are 0
        } else {
            Z[zs(k)]  = make_float2(xkr, xki);
            Z[zs(km)] = make_float2(xmr, xmi); // k==2048: same slot, same value
        }
    }
    __syncthreads();

    // Pass B: keep-mask on squared mags + repack filtered half-spectrum; write CONJ
    // (inverse FFT = conj(FFT(conj(X)))/M)
    for (int k = tid; k <= 2048; k += 512) {
        const int km = (MFFT - k) & (MFFT - 1);
        float xkr, xki, xmr, xmi;
        if (k == 0) {
            const float2 v = Z[zs(0)];
            xkr = v.x; xki = 0.0f; xmr = v.y; xmi = 0.0f;
        } else {
            const float2 a = Z[zs(k)];
            const float2 b = Z[zs(km)];
            xkr = a.x; xki = a.y; xmr = b.x; xmi = b.y;
        }
        const float2 u = U[k];
        const float cs = u.x, sn = u.y;        // theta = +pi k/4096
        const int jm = MFFT - k;
        bool keepk, keepm;
        {
            const int lo = (k - 3 < 0) ? 0 : k - 3;
            const int hi = (k + 4 > 4096) ? 4096 : k + 4;
            float mx = mg[k];
            for (int t2 = lo; t2 <= hi; ++t2) mx = fmaxf(mx, mg[t2]);
            keepk = (k < 3) || (mg[k] >= mx);
        }
        {
            const int hi = (jm + 4 > 4096) ? 4096 : jm + 4;
            float mx = mg[jm];
            for (int t2 = jm - 3; t2 <= hi; ++t2) mx = fmaxf(mx, mg[t2]);
            keepm = (mg[jm] >= mx);
        }
        if (!keepk) { xkr = 0.0f; xki = 0.0f; }
        if (!keepm) { xmr = 0.0f; xmi = 0.0f; }
        const float zpex = 0.5f * (xkr + xmr), zpey = 0.5f * (xki - xmi);
        const float dfx  = 0.5f * (xkr - xmr), dfy  = 0.5f * (xki + xmi);
        const float zpox = dfx * cs - dfy * sn, zpoy = dfx * sn + dfy * cs;
        const float2 zk = make_float2(zpex - zpoy, zpey + zpox);
        const float zex3 = 0.5f * (xmr + xkr), zey3 = 0.5f * (xmi - xki);
        const float df2x = 0.5f * (xmr - xkr), df2y = 0.5f * (xmi + xki);
        const float zo3x = -df2x * cs - df2y * sn, zo3y = df2x * sn - df2y * cs;
        const float2 zm = make_float2(zex3 - zo3y, zey3 + zo3x);
        Z[zs(k)] = make_float2(zk.x, -zk.y);
        if (k != 0 && k != 2048) Z[zs(MFFT - k)] = make_float2(zm.x, -zm.y);
    }
    __syncthreads();

    fft4096(Z, tw, tid);              // FFT(conj(Z')) -> conj + scale at store

    const float invM = 1.0f / (float)MFFT;
    for (int m = tid; m < MFFT; m += 512) {
        const float2 z = Z[zs(m)];
        *(float2*)&row[2 * m] = make_float2(z.x * invM, -z.y * invM);
    }
}

// ---------------- K3: transpose back * filt_w, LN2, cast bf16 --------------
__global__ __launch_bounds__(256) void k3_filt_ln2(const float* __restrict__ ht,
                                                   const float* __restrict__ fw,
                                                   const float* __restrict__ g2,
                                                   const float* __restrict__ b2,
                                                   bf16* __restrict__ aln) {
    __shared__ float tile[DDIM][33];
    const int tid  = threadIdx.x;
    const int wave = tid >> 6, lane = tid & 63;
    const int b  = blockIdx.x >> 8;
    const int l0 = (blockIdx.x & 255) << 5;
    for (int i = tid; i < DDIM * 32; i += 256) {
        const int d = i >> 5, ll = i & 31;
        tile[d][ll] = ht[(b * DDIM + d) * LSEQ + l0 + ll];
    }
    __syncthreads();
    const float4 g4 = *(const float4*)&g2[lane * 4];
    const float4 bb4 = *(const float4*)&b2[lane * 4];
    for (int r8 = 0; r8 < 8; ++r8) {
        const int l = r8 * 4 + wave;
        const int gl = l0 + l;
        const float4 f4 = *(const float4*)&fw[gl * DDIM + lane * 4];
        float v[4];
        v[0] = tile[lane * 4 + 0][l] * f4.x;
        v[1] = tile[lane * 4 + 1][l] * f4.y;
        v[2] = tile[lane * 4 + 2][l] * f4.z;
        v[3] = tile[lane * 4 + 3][l] * f4.w;
        float s = v[0] + v[1] + v[2] + v[3];
        float q = v[0] * v[0] + v[1] * v[1] + v[2] * v[2] + v[3] * v[3];
        wave_reduce2(s, q);
        const float mean = s * (1.0f / 256.0f);
        const float var  = q * (1.0f / 256.0f) - mean * mean;
        const float rstd = rsqrtf(var + 1e-5f);
        const float gg[4] = {g4.x, g4.y, g4.z, g4.w};
        const float bb[4] = {bb4.x, bb4.y, bb4.z, bb4.w};
        bf16x4 o;
        #pragma unroll
        for (int j = 0; j < 4; ++j)
            o[j] = (bf16)((v[j] - mean) * rstd * gg[j] + bb[j]);
        *(bf16x4*)&aln[(b * LSEQ + gl) * DDIM + lane * 4] = o;
    }
}

// ---------------- K4: fused MLP (r11 verbatim — best measured 112.4 us) ----
// GEMM1 16x16x32 (A-resident), GEMM2 32x32x16. Block 64 rows, 8 waves.
// LDS: W1 [ks 0..7][grp 0..3][hh 0..63][8] bf16 @0      (32 KB)
//      W2 [ks4 0..3][g2 0..1][d 0..255][8] bf16 @32768  (32 KB)
//      lM [ks4 0..3][g2 0..1][row 0..63][8] bf16 @65536 ( 8 KB)
#define LDS_W1 0
#define LDS_W2 32768
#define LDS_LM 65536
#define LDS_TOT 73728

#define MFMA16 __builtin_amdgcn_mfma_f32_16x16x32_bf16
#define MFMA32 __builtin_amdgcn_mfma_f32_32x32x16_bf16

__global__ __launch_bounds__(512, 4) void k4_mlp(const bf16* __restrict__ aln,
                                                 const bf16* __restrict__ w1k,
                                                 const bf16* __restrict__ w2k,
                                                 const float* __restrict__ bb1,
                                                 const float* __restrict__ bb2,
                                                 const float* __restrict__ x,
                                                 float* __restrict__ out) {
    extern __shared__ char sm[];
    const int tid = threadIdx.x;
    const int lane = tid & 63, w = tid >> 6;
    const int rowLane = lane & 15, grp = lane >> 4;
    const int wm1 = w >> 1, wn1 = w & 1;      // G1 role: 4M x 2N, 16-row waves
    const int wm2 = w >> 2, wn2 = w & 3;      // G2 role: 2M x 4N, 32-row waves
    const int lane32 = lane & 31, g2l = lane >> 5;
    const int row0 = blockIdx.x << 6;         // 64 rows per block

    // A fragments: wave's 16 rows x 256 K slice, 32 VGPRs (r7/r10-proven)
    bf16x8 aF[8];
    {
        const size_t rb = (size_t)(row0 + wm1 * 16 + rowLane) * DDIM;
        #pragma unroll
        for (int ks = 0; ks < 8; ++ks)
            aF[ks] = *(const bf16x8*)(aln + rb + ks * 32 + grp * 8);
    }
    // prologue: stage W1 chunk 0 (32 KB linear)
    {
        const char* g1 = (const char*)w1k;
        #pragma unroll
        for (int r = 0; r < 4; ++r)
            gl_lds16(g1 + r * 8192 + tid * 16, sm + LDS_W1 + r * 8192 + tid * 16);
    }
    __syncthreads();

    f32x16 acc0, acc1;
    #pragma unroll
    for (int i = 0; i < 16; ++i) { acc0[i] = 0.f; acc1[i] = 0.f; }

    for (int c = 0; c < 16; ++c) {
        // stage W2 chunk c (drains at barrier1)
        {
            const char* g2p = (const char*)w2k + (size_t)c * 32768;
            #pragma unroll
            for (int r = 0; r < 4; ++r)
                gl_lds16(g2p + r * 8192 + tid * 16, sm + LDS_W2 + r * 8192 + tid * 16);
        }
        const int hc0 = wn1 * 32 + rowLane;         // wave's first hcol group

        // ---- GEMM1: P(16x32/wave) = Areg(16x256) x W1c; aF reused for p0,p1
        f32x4 p0 = {0.f, 0.f, 0.f, 0.f}, p1 = p0;
        #pragma unroll
        for (int ks = 0; ks < 8; ++ks) {
            const bf16x8 b0 = *(const bf16x8*)(sm + LDS_W1 + ks * 4096 + grp * 1024 + hc0 * 16);
            const bf16x8 b1 = *(const bf16x8*)(sm + LDS_W1 + ks * 4096 + grp * 1024 + (hc0 + 16) * 16);
            p0 = MFMA16(aF[ks], b0, p0, 0, 0, 0);
            p1 = MFMA16(aF[ks], b1, p1, 0, 0, 0);
        }
        // ---- bias + exact gelu -> lM [ks4][g2][row][8]
        {
            const float bias0 = bb1[c * 64 + hc0];
            const float bias1 = bb1[c * 64 + hc0 + 16];
            const int hc1 = hc0 + 16;
            const int base0 = (((hc0 >> 4) * 2 + ((hc0 >> 3) & 1)) * 64) * 16 + (hc0 & 7) * 2;
            const int base1 = (((hc1 >> 4) * 2 + ((hc1 >> 3) & 1)) * 64) * 16 + (hc1 & 7) * 2;
            #pragma unroll
            for (int j = 0; j < 4; ++j) {
                const int prow = wm1 * 16 + grp * 4 + j;
                const float v0 = p0[j] + bias0;
                const float ge0 = 0.5f * v0 * (1.0f + erff(v0 * 0.70710678118654752f));
                *(bf16*)(sm + LDS_LM + base0 + prow * 16) = (bf16)ge0;
                const float v1 = p1[j] + bias1;
                const float ge1 = 0.5f * v1 * (1.0f + erff(v1 * 0.70710678118654752f));
                *(bf16*)(sm + LDS_LM + base1 + prow * 16) = (bf16)ge1;
            }
        }
        __syncthreads();   // lM visible; W2 staging drained; G1 done with W1
        // stage W1 chunk c+1 under G2's cover
        if (c < 15) {
            const char* g1 = (const char*)w1k + (size_t)(c + 1) * 32768;
            #pragma unroll
            for (int r = 0; r < 4; ++r)
                gl_lds16(g1 + r * 8192 + tid * 16, sm + LDS_W1 + r * 8192 + tid * 16);
        }
        // ---- GEMM2 (32x32x16): acc(32x64/wave) += lM(32 x 64h) x W2c
        #pragma unroll
        for (int ks4 = 0; ks4 < 4; ++ks4) {
            const int plane = (ks4 * 2 + g2l);
            const bf16x8 aM = *(const bf16x8*)(sm + LDS_LM + (plane * 64 + wm2 * 32 + lane32) * 16);
            const bf16x8 bw0 = *(const bf16x8*)(sm + LDS_W2 + (plane * 256 + wn2 * 64 + lane32) * 16);
            const bf16x8 bw1 = *(const bf16x8*)(sm + LDS_W2 + (plane * 256 + wn2 * 64 + 32 + lane32) * 16);
            acc0 = MFMA32(aM, bw0, acc0, 0, 0, 0);
            acc1 = MFMA32(aM, bw1, acc1, 0, 0, 0);
        }
        __syncthreads();   // G2 done with lM/W2; W1 staging drained
    }
    // ---- epilogue: +bb2 + residual.  32x32 C/D: col=lane&31,
    // row = (reg&3) + 8*(reg>>2) + 4*(lane>>5)   [m74/m101 verified]
    #pragma unroll
    for (int fn = 0; fn < 2; ++fn) {
        const int dcol = wn2 * 64 + fn * 32 + lane32;
        const float b2v = bb2[dcol];
        #pragma unroll
        for (int reg = 0; reg < 16; ++reg) {
            const int orow = row0 + wm2 * 32 + (reg & 3) + 8 * (reg >> 2) + 4 * g2l;
            const int gi = orow * DDIM + dcol;
            const float a = fn ? acc1[reg] : acc0[reg];
            out[gi] = a + b2v + x[gi];
        }
    }
}

extern "C" void kernel_launch(void* const* d_in, const int* in_sizes, int n_in,
                              void* d_out, int out_size, void* d_ws, size_t ws_size,
                              hipStream_t stream) {
    (void)in_sizes; (void)n_in; (void)out_size; (void)ws_size;
    const float* x   = (const float*)d_in[0];
    const float* g1  = (const float*)d_in[1];
    const float* b1  = (const float*)d_in[2];
    const float* g2  = (const float*)d_in[3];
    const float* b2  = (const float*)d_in[4];
    const float* fw  = (const float*)d_in[5];
    const float* w1  = (const float*)d_in[6];
    const float* bb1 = (const float*)d_in[7];
    const float* w2  = (const float*)d_in[8];
    const float* bb2 = (const float*)d_in[9];
    float* out = (float*)d_out;
    char*  ws  = (char*)d_ws;

    bf16*   aln = (bf16*)ws;                             // 33554432 B
    bf16*   w1k = (bf16*)(ws + (size_t)33554432);        //   524288 B
    bf16*   w2k = (bf16*)(ws + (size_t)34078720);        //   524288 B
    float2* tbl = (float2*)(ws + (size_t)34603008);      //    65480 B
    float* ht = out;                                     // reuse d_out as (B,D,L) scratch

    k0_prep<<<dim3(1024), dim3(256), 0, stream>>>(w1, w2, w1k, w2k, tbl);
    k1_ln1_relu_T<<<dim3(2048), dim3(256), 0, stream>>>(x, g1, b1, ht);
    k2_spsd<<<dim3(2048), dim3(512), 0, stream>>>(ht, tbl);
    k3_filt_ln2<<<dim3(2048), dim3(256), 0, stream>>>(ht, fw, g2, b2, aln);
    k4_mlp<<<dim3(1024), dim3(512), LDS_TOT, stream>>>(aln, w1k, w2k, bb1, bb2, x, out);
}